// Round 7
// baseline (896.124 us; speedup 1.0000x reference)
//
#include <hip/hip_runtime.h>

// ---------------------------------------------------------------------------
// LightGCN on MI355X — round 6.
//  - z0 built per-plane IMMEDIATELY before its chunk's SpMM chain so the
//    gather source is L3-fresh (R5 wrote both planes up front; chunk 1's
//    plane was evicted by ~600us of intervening writes).
//  - Nontemporal stores for `out` (single-use 256MB stream) and nontemporal
//    loads for `emb` (single-use 256MB stream) to stop polluting L3, keeping
//    z buffers + ci resident for the random gathers.
//  - deg_rank kept as-is: 4M device atomics = 4M x 32B HBM granule writes
//    (~148us floor, measured 157us) — structurally op-count-bound.
//  - u8-packed degree counters, atomic-free XCD-sliced fill, bf16 pre-scaled
//    z-recurrence, W=32 chunks, fused final layer + epilogue (as R5).
// ---------------------------------------------------------------------------

#define BLK 256
#define SCAN_CHUNK 2048
#define FILL_EPB 2048     // edges per fill block chunk

typedef unsigned int u32;
typedef unsigned char u8;
typedef float  __attribute__((ext_vector_type(4))) f32x4;
typedef u32    __attribute__((ext_vector_type(4))) u32x4;

static inline int nblk(long long total) { return (int)((total + BLK - 1) / BLK); }

// round-to-nearest-even pack of two f32 into bf16x2
__device__ inline u32 pack_bf2(float lo, float hi) {
    u32 a = __float_as_uint(lo);
    u32 b = __float_as_uint(hi);
    a = a + 0x7fffu + ((a >> 16) & 1u);
    b = b + 0x7fffu + ((b >> 16) & 1u);
    return (a >> 16) | (b & 0xffff0000u);
}

__device__ inline void unpack_acc(uint4 w, float* a) {
    a[0] += __uint_as_float(w.x << 16);
    a[1] += __uint_as_float(w.x & 0xffff0000u);
    a[2] += __uint_as_float(w.y << 16);
    a[3] += __uint_as_float(w.y & 0xffff0000u);
    a[4] += __uint_as_float(w.z << 16);
    a[5] += __uint_as_float(w.z & 0xffff0000u);
    a[6] += __uint_as_float(w.w << 16);
    a[7] += __uint_as_float(w.w & 0xffff0000u);
}

__device__ inline void unpack8(uint4 w, float* a) {
    a[0] = __uint_as_float(w.x << 16);
    a[1] = __uint_as_float(w.x & 0xffff0000u);
    a[2] = __uint_as_float(w.y << 16);
    a[3] = __uint_as_float(w.y & 0xffff0000u);
    a[4] = __uint_as_float(w.z << 16);
    a[5] = __uint_as_float(w.z & 0xffff0000u);
    a[6] = __uint_as_float(w.w << 16);
    a[7] = __uint_as_float(w.w & 0xffff0000u);
}

// ---- degree (u8-packed) + per-edge rank ----------------------------------
__global__ void deg_rank_kernel(const int* __restrict__ uid,
                                const int* __restrict__ iid,
                                int E, int n_users,
                                u32* __restrict__ degw,   // u8 counters, word-packed
                                u32* __restrict__ rank2) {
    int t = blockIdx.x * blockDim.x + threadIdx.x;
    if (t < E) {
        u32 u  = (u32)uid[t];
        u32 iN = (u32)(n_users + iid[t]);
        u32 su = 8u * (u & 3u), si = 8u * (iN & 3u);
        u32 r0 = atomicAdd(&degw[u >> 2],  1u << su);
        u32 r1 = atomicAdd(&degw[iN >> 2], 1u << si);
        r0 = (r0 >> su) & 0xffu;
        r1 = (r1 >> si) & 0xffu;
        rank2[t] = r0 | (r1 << 16);
    }
}

__global__ void dinv_kernel(const u8* __restrict__ deg8,
                            float* __restrict__ dinv, int n_nodes) {
    int t = blockIdx.x * blockDim.x + threadIdx.x;
    if (t < n_nodes) dinv[t] = rsqrtf((float)deg8[t] + 1e-8f);
}

// ---- prefix scan over u8 degrees: rp[i+1] = incl_sum(deg8[0..i]) ---------
__global__ void scan1_kernel(const u8* __restrict__ deg8,
                             u32* __restrict__ rp, u32* __restrict__ bsum, int n) {
    __shared__ u32 ts[256];
    int tid = threadIdx.x;
    int base = blockIdx.x * SCAN_CHUNK + tid * 8;
    u32 v[8];
    u32 s = 0;
    #pragma unroll
    for (int i = 0; i < 8; ++i) {
        v[i] = (base + i < n) ? (u32)deg8[base + i] : 0u;
        s += v[i];
    }
    ts[tid] = s;
    __syncthreads();
    for (int off = 1; off < 256; off <<= 1) {
        u32 a = (tid >= off) ? ts[tid - off] : 0u;
        __syncthreads();
        ts[tid] += a;
        __syncthreads();
    }
    u32 run = (tid > 0) ? ts[tid - 1] : 0u;
    #pragma unroll
    for (int i = 0; i < 8; ++i) {
        run += v[i];
        if (base + i < n) rp[base + i + 1] = run;
    }
    if (tid == 255) bsum[blockIdx.x] = ts[255];
}

__global__ void scan2_kernel(u32* __restrict__ bsum, int nb) {
    __shared__ u32 s[1024];
    int tid = threadIdx.x;
    s[tid] = (tid < nb) ? bsum[tid] : 0u;
    __syncthreads();
    for (int off = 1; off < 1024; off <<= 1) {
        u32 a = (tid >= off) ? s[tid - off] : 0u;
        __syncthreads();
        s[tid] += a;
        __syncthreads();
    }
    if (tid < nb) bsum[tid] = (tid == 0) ? 0u : s[tid - 1];
}

__global__ void scan3_kernel(u32* __restrict__ rp,
                             const u32* __restrict__ bsum, int n) {
    int t = blockIdx.x * blockDim.x + threadIdx.x;
    if (t < n) rp[t + 1] += bsum[t / SCAN_CHUNK];
    if (t == 0) rp[0] = 0u;
}

// ---- atomic-free, XCD-sliced CSR fill ------------------------------------
__global__ void fill_sliced_kernel(const int* __restrict__ uid,
                                   const int* __restrict__ iid,
                                   const u32* __restrict__ rank2,
                                   const u32* __restrict__ rp,
                                   int E, int n_users, int shift,
                                   int* __restrict__ ci) {
    int slice = blockIdx.x & 7;
    int chunk = blockIdx.x >> 3;
    int e0   = chunk * FILL_EPB;
    int eend = min(E, e0 + FILL_EPB);
    for (int e = e0 + threadIdx.x; e < eend; e += BLK) {
        int u  = uid[e];
        int iN = n_users + iid[e];
        u32 rr = rank2[e];
        if ((u >> shift) == slice)  ci[rp[u]  + (rr & 0xffffu)] = iN;
        if ((iN >> shift) == slice) ci[rp[iN] + (rr >> 16)]     = u;
    }
}

// ---- z0 plane p: z0p[row] = bf16(dinv[row] * emb[row, 32p:32p+32]) --------
// Nontemporal emb loads: 256MB single-use stream must not evict z buffers.
__global__ void z0_plane_kernel(const f32x4* __restrict__ uemb,
                                const f32x4* __restrict__ iemb,
                                const float* __restrict__ dinv,
                                uint4* __restrict__ z0p, int plane,
                                int n_users, int n_nodes) {
    long long t = (long long)blockIdx.x * blockDim.x + threadIdx.x;
    if (t >= (long long)n_nodes * 4) return;
    int row = (int)(t >> 2);
    int j4  = (int)(t & 3);
    const f32x4* src = (row < n_users)
                           ? uemb + (size_t)row * 16 + plane * 8 + j4 * 2
                           : iemb + (size_t)(row - n_users) * 16 + plane * 8 + j4 * 2;
    f32x4 p = __builtin_nontemporal_load(src);
    f32x4 q = __builtin_nontemporal_load(src + 1);
    float w = dinv[row];
    uint4 o;
    o.x = pack_bf2(w * p.x, w * p.y);
    o.y = pack_bf2(w * p.z, w * p.w);
    o.z = pack_bf2(w * q.x, w * q.y);
    o.w = pack_bf2(w * q.z, w * q.w);
    z0p[(size_t)row * 4 + j4] = o;
}

// ---- middle layers: dst = bf16( dinv^2 * sum_{c} src[c] ), 64B rows -------
__global__ void spmm_mid(const u32* __restrict__ rp,
                         const int* __restrict__ ci,
                         const float* __restrict__ dinv,
                         const uint4* __restrict__ src,
                         uint4* __restrict__ dst, int n_nodes) {
    long long t = (long long)blockIdx.x * blockDim.x + threadIdx.x;
    int row = (int)(t >> 2);
    if (row >= n_nodes) return;
    int j = (int)(t & 3);
    const uint4* sp = src + j;
    u32 k = rp[row], end = rp[row + 1];
    float a[8] = {0.f, 0.f, 0.f, 0.f, 0.f, 0.f, 0.f, 0.f};
    for (; k + 3 < end; k += 4) {
        int c0 = ci[k], c1 = ci[k + 1], c2 = ci[k + 2], c3 = ci[k + 3];
        uint4 w0 = sp[(size_t)c0 * 4];
        uint4 w1 = sp[(size_t)c1 * 4];
        uint4 w2 = sp[(size_t)c2 * 4];
        uint4 w3 = sp[(size_t)c3 * 4];
        unpack_acc(w0, a); unpack_acc(w1, a);
        unpack_acc(w2, a); unpack_acc(w3, a);
    }
    for (; k < end; ++k) {
        uint4 w0 = sp[(size_t)ci[k] * 4];
        unpack_acc(w0, a);
    }
    float dr = dinv[row];
    float s = dr * dr;
    uint4 o;
    o.x = pack_bf2(s * a[0], s * a[1]);
    o.y = pack_bf2(s * a[2], s * a[3]);
    o.z = pack_bf2(s * a[4], s * a[5]);
    o.w = pack_bf2(s * a[6], s * a[7]);
    dst[(size_t)row * 4 + j] = o;
}

// ---- layer 3 + fused epilogue (nontemporal out stores) --------------------
__global__ void spmm_final(const u32* __restrict__ rp,
                           const int* __restrict__ ci,
                           const float* __restrict__ dinv,
                           const uint4* __restrict__ z2,
                           const uint4* __restrict__ z1,
                           const uint4* __restrict__ z0p,  // this chunk's plane
                           f32x4* __restrict__ out, int f4base, int n_nodes) {
    long long t = (long long)blockIdx.x * blockDim.x + threadIdx.x;
    int row = (int)(t >> 2);
    if (row >= n_nodes) return;
    int j = (int)(t & 3);
    const uint4* sp = z2 + j;
    u32 k = rp[row], end = rp[row + 1];
    float a[8] = {0.f, 0.f, 0.f, 0.f, 0.f, 0.f, 0.f, 0.f};
    for (; k + 3 < end; k += 4) {
        int c0 = ci[k], c1 = ci[k + 1], c2 = ci[k + 2], c3 = ci[k + 3];
        uint4 w0 = sp[(size_t)c0 * 4];
        uint4 w1 = sp[(size_t)c1 * 4];
        uint4 w2 = sp[(size_t)c2 * 4];
        uint4 w3 = sp[(size_t)c3 * 4];
        unpack_acc(w0, a); unpack_acc(w1, a);
        unpack_acc(w2, a); unpack_acc(w3, a);
    }
    for (; k < end; ++k) {
        uint4 w0 = sp[(size_t)ci[k] * 4];
        unpack_acc(w0, a);
    }
    float dr = dinv[row];
    float inv = 1.0f / dr;

    float v0[8], v1[8], v2[8];
    unpack8(z0p[(size_t)row * 4 + j], v0);
    unpack8(z1[(size_t)row * 4 + j], v1);
    unpack8(z2[(size_t)row * 4 + j], v2);

    float r[8];
    #pragma unroll
    for (int i = 0; i < 8; ++i)
        r[i] = 0.25f * ((v0[i] + v1[i] + v2[i]) * inv + dr * a[i]);

    size_t ob = (size_t)row * 16 + f4base + j * 2;
    f32x4 lo = {r[0], r[1], r[2], r[3]};
    f32x4 hi = {r[4], r[5], r[6], r[7]};
    __builtin_nontemporal_store(lo, out + ob);
    __builtin_nontemporal_store(hi, out + ob + 1);
}

// ---------------------------------------------------------------------------
extern "C" void kernel_launch(void* const* d_in, const int* in_sizes, int n_in,
                              void* d_out, int out_size, void* d_ws, size_t ws_size,
                              hipStream_t stream) {
    const float* uemb = (const float*)d_in[0];
    const float* iemb = (const float*)d_in[1];
    const int*   uid  = (const int*)d_in[2];
    const int*   iid  = (const int*)d_in[3];

    const int d = 64;
    int n_users = in_sizes[0] / d;
    int n_items = in_sizes[1] / d;
    int E       = in_sizes[2];
    int n_nodes = n_users + n_items;
    long long nnz = 2LL * E;

    auto align256 = [](size_t x) { return (x + 255) & ~(size_t)255; };
    size_t deg_b  = align256((size_t)n_nodes + 4);       // u8 counters
    size_t rp_b   = align256((size_t)(n_nodes + 1) * 4);
    size_t dinv_b = align256((size_t)n_nodes * 4);
    size_t ci_b   = align256((size_t)nnz * 4);
    size_t rk_b   = align256((size_t)E * 4);
    size_t bs_b   = align256(4096 * 4);
    size_t z0_b   = align256((size_t)n_nodes * 128);     // 2 planes x 64B
    size_t z_b    = align256((size_t)n_nodes * 64);      // 32 bf16 per row

    char* p = (char*)d_ws;
    u32*   degw  = (u32*)p;    p += deg_b;
    u32*   rp    = (u32*)p;    p += rp_b;
    float* dinv  = (float*)p;  p += dinv_b;
    int*   ci    = (int*)p;    p += ci_b;
    u32*   rank2 = (u32*)p;    p += rk_b;
    u32*   bsum  = (u32*)p;    p += bs_b;
    uint4* z0    = (uint4*)p;  p += z0_b;
    uint4* z1    = (uint4*)p;  p += z_b;
    uint4* z2    = (uint4*)p;
    size_t plane4 = (size_t)n_nodes * 4;   // uint4s per z0 plane

    // node-range slice shift for fill: slice = row >> shift in [0,8)
    int shift = 0;
    while (((n_nodes - 1) >> shift) >= 8) shift++;

    // ---- degrees (u8, + per-edge ranks), dinv ----
    hipMemsetAsync(degw, 0, (size_t)n_nodes + 4, stream);
    deg_rank_kernel<<<nblk(E), BLK, 0, stream>>>(uid, iid, E, n_users, degw, rank2);
    dinv_kernel<<<nblk(n_nodes), BLK, 0, stream>>>((const u8*)degw, dinv, n_nodes);

    // ---- prefix scan deg8 -> rp ----
    int nb = (n_nodes + SCAN_CHUNK - 1) / SCAN_CHUNK;
    scan1_kernel<<<nb, 256, 0, stream>>>((const u8*)degw, rp, bsum, n_nodes);
    scan2_kernel<<<1, 1024, 0, stream>>>(bsum, nb);
    scan3_kernel<<<nblk(n_nodes), BLK, 0, stream>>>(rp, bsum, n_nodes);

    // ---- atomic-free XCD-sliced CSR fill ----
    int nchunks = (E + FILL_EPB - 1) / FILL_EPB;
    fill_sliced_kernel<<<nchunks * 8, BLK, 0, stream>>>(
        uid, iid, rank2, rp, E, n_users, shift, ci);

    // ---- per feature-chunk (W=32): z0 plane built just-in-time, then the
    //      3 gather layers (last fused with epilogue).
    f32x4* out4 = (f32x4*)d_out;
    long long nt = (long long)n_nodes * 4;
    for (int c = 0; c < 2; ++c) {
        uint4* z0p = z0 + (size_t)c * plane4;
        int f4base = c * 8;   // float4 offset into out row
        z0_plane_kernel<<<nblk(nt), BLK, 0, stream>>>(
            (const f32x4*)uemb, (const f32x4*)iemb, dinv, z0p, c,
            n_users, n_nodes);
        spmm_mid<<<nblk(nt), BLK, 0, stream>>>(rp, ci, dinv, z0p, z1, n_nodes);
        spmm_mid<<<nblk(nt), BLK, 0, stream>>>(rp, ci, dinv, z1, z2, n_nodes);
        spmm_final<<<nblk(nt), BLK, 0, stream>>>(rp, ci, dinv, z2, z1, z0p,
                                                 out4, f4base, n_nodes);
    }
}